// Round 4
// baseline (156.112 us; speedup 1.0000x reference)
//
#include <hip/hip_runtime.h>
#include <math.h>

#define B_SZ   1024
#define N_SZ   128
#define M_SZ   256
#define I_SZ   64
#define WPB    16              // waves per block (i-chunks)
#define CHI    (I_SZ / WPB)    // 4 i's per wave
#define BPB    4               // b's per block (one per 16-lane group)

// tbl[i*M + m] = (cos w0, sin w0, cos w1, sin w1), w0=weight[m][2i], w1=weight[m][2i+1]
__global__ void precompute_tbl(const float* __restrict__ weight,
                               float4* __restrict__ tbl) {
    int tid = blockIdx.x * blockDim.x + threadIdx.x;   // 0..16383
    int i = tid >> 8, m = tid & 255;
    float w0 = weight[m * N_SZ + 2 * i];
    float w1 = weight[m * N_SZ + 2 * i + 1];
    float c0, s0, c1, s1;
    __sincosf(w0, &s0, &c0);
    __sincosf(w1, &s1, &c1);
    tbl[i * M_SZ + m] = make_float4(c0, s0, c1, s1);
}

// One block = 4 samples x 16 i-chunk waves. Lane layout: bl = lane>>4 picks the
// sample, ml = lane&15; lane owns m = ml + 16t, t=0..15. Main loop is pure FMA
// (rotation recurrence, no trans); m-reduction is a 4-step butterfly serving
// 4 b's per DS instruction. Chunk z-starts via cooperative LDS exclusive scan.
__global__ __launch_bounds__(1024) void arrbm_main(
    const float* __restrict__ vis,     // [B,N]
    const float* __restrict__ hb,      // [M]
    const float* __restrict__ weight,  // [M,N]
    const float4* __restrict__ tbl,    // [I,M]
    float* __restrict__ out)           // [B]
{
    const int tid  = threadIdx.x;
    const int wv   = tid >> 6;          // 0..15 : i-chunk index
    const int lane = tid & 63;
    const int bl   = lane >> 4;         // 0..3 : sample within block
    const int ml   = lane & 15;         // m = ml + 16*t

    __shared__ float  s_vis[BPB * N_SZ];        // 2 KB
    __shared__ float4 s_scan[WPB * 4 * 64];     // 64 KB
    __shared__ float2 s_red[WPB][BPB];
    __shared__ float  s_sz[BPB];

    if (tid < BPB * N_SZ)
        s_vis[tid] = vis[blockIdx.x * (BPB * N_SZ) + tid];
    __syncthreads();

    // Sz filter (wave 0, parallel)
    if (wv == 0) {
        float d = 0.f;
        #pragma unroll
        for (int k = 0; k < 4; ++k)
            d += s_vis[bl * N_SZ + 8 * ml + 2 * k] - s_vis[bl * N_SZ + 8 * ml + 2 * k + 1];
        #pragma unroll
        for (int off = 1; off <= 8; off <<= 1)
            d += __shfl_xor(d, off, 64);
        if (ml == 0) s_sz[bl] = d;
    }

    const int i0 = wv * CHI;

    float v0[CHI], v1[CHI], pm[CHI];
    #pragma unroll
    for (int j = 0; j < CHI; ++j) {
        v0[j] = s_vis[bl * N_SZ + 2 * (i0 + j)];
        v1[j] = s_vis[bl * N_SZ + 2 * (i0 + j) + 1];
        pm[j] = v0[j] * v1[j];
    }

    // local chunk step-sum per owned m
    float ls[16];
    #pragma unroll
    for (int t = 0; t < 16; ++t) {
        const int m = ml + 16 * t;
        const float4* wrow = (const float4*)(weight + (size_t)m * N_SZ) + (i0 >> 1);
        float a = 0.f;
        #pragma unroll
        for (int k = 0; k < CHI / 2; ++k) {
            float4 w4 = wrow[k];
            a += v0[2*k]   * w4.x + v1[2*k]   * w4.y
               + v0[2*k+1] * w4.z + v1[2*k+1] * w4.w;
        }
        ls[t] = a;
    }

    // exclusive scan across waves -> z at chunk start
    #pragma unroll
    for (int k = 0; k < 4; ++k)
        s_scan[(wv * 4 + k) * 64 + lane] =
            make_float4(ls[4*k], ls[4*k+1], ls[4*k+2], ls[4*k+3]);
    __syncthreads();

    float z0[16];
    #pragma unroll
    for (int t = 0; t < 16; ++t) z0[t] = 0.f;
    for (int wp = 0; wp < wv; ++wp) {
        #pragma unroll
        for (int k = 0; k < 4; ++k) {
            float4 r = s_scan[(wp * 4 + k) * 64 + lane];
            z0[4*k]   += r.x; z0[4*k+1] += r.y;
            z0[4*k+2] += r.z; z0[4*k+3] += r.w;
        }
    }

    // init rotation state at chunk start; only trans ops in this kernel
    float c[16], s[16];
    float pstart = 1.f;
    #pragma unroll
    for (int t = 0; t < 16; ++t) {
        float pre = hb[ml + 16 * t] + z0[t];
        __sincosf(pre, &s[t], &c[t]);
        pstart *= c[t];
    }

    float psi = 1.f, acc = 1.f;
    #pragma unroll
    for (int j = 0; j < CHI; ++j) {
        const int i = i0 + j;
        const float4* trow = tbl + i * M_SZ + ml;
        float q0 = 1.f, q1 = 1.f, q2 = 1.f;
        #pragma unroll
        for (int t = 0; t < 16; ++t) {
            float4 w = trow[16 * t];
            float pw0 = fmaf(-s[t], w.y, c[t] * w.x);   // cos(pre+w0)
            float pw1 = fmaf(-s[t], w.w, c[t] * w.z);   // cos(pre+w1)
            q0 *= c[t]; q1 *= pw0; q2 *= pw1;
            float cs = fmaf(-pm[j], w.y * w.w, w.x * w.z);          // cos(step)
            float ss = fmaf(v1[j], w.x * w.w, v0[j] * (w.y * w.z)); // sin(step)
            float cn = fmaf(-s[t], ss, c[t] * cs);
            float sn = fmaf( c[t], ss, s[t] * cs);
            c[t] = cn; s[t] = sn;
        }
        #pragma unroll
        for (int off = 1; off <= 8; off <<= 1) {
            q0 *= __shfl_xor(q0, off, 64);
            q1 *= __shfl_xor(q1, off, 64);
            q2 *= __shfl_xor(q2, off, 64);
        }
        float n2 = 4.f * q0 * q0 + 2.f * q1 * q1 + 2.f * q2 * q2;
        acc *= rsqrtf(n2);
        psi *= q0;          // group-uniform after butterfly
    }

    // chunk telescope correction: x prod_m c_end/c_start
    float pend = 1.f;
    #pragma unroll
    for (int t = 0; t < 16; ++t) pend *= c[t];
    float r = pend / pstart;
    #pragma unroll
    for (int off = 1; off <= 8; off <<= 1)
        r *= __shfl_xor(r, off, 64);
    psi *= r;

    if (ml == 0) s_red[wv][bl] = make_float2(psi, acc);
    __syncthreads();

    if (tid < BPB) {
        float P = 1.f;
        #pragma unroll
        for (int w = 0; w < WPB; ++w)
            P *= s_red[w][tid].x * s_red[w][tid].y;
        out[blockIdx.x * BPB + tid] = (s_sz[tid] != 0.f) ? 0.f : P;
    }
}

extern "C" void kernel_launch(void* const* d_in, const int* in_sizes, int n_in,
                              void* d_out, int out_size, void* d_ws, size_t ws_size,
                              hipStream_t stream) {
    const float* vis    = (const float*)d_in[0];  // [B,N]
    const float* hb     = (const float*)d_in[1];  // [M]
    const float* weight = (const float*)d_in[2];  // [M,N]
    float* out  = (float*)d_out;                  // [B]
    float4* tbl = (float4*)d_ws;                  // [I*M] = 256 KB

    precompute_tbl<<<64, 256, 0, stream>>>(weight, tbl);
    arrbm_main<<<B_SZ / BPB, 64 * WPB, 0, stream>>>(vis, hb, weight, tbl, out);
}

// Round 5
// 113.375 us; speedup vs baseline: 1.3770x; 1.3770x over previous
//
#include <hip/hip_runtime.h>
#include <math.h>

#define B_SZ   1024
#define N_SZ   128
#define M_SZ   256
#define I_SZ   64
#define WPB    8               // waves per block (i-chunks)
#define CHI    (I_SZ / WPB)    // 8 i's per wave
#define BPB    4               // b's per block (one per 16-lane group)

// tbl[i*M + m] = (cos w0, sin w0, cos w1, sin w1), w0=weight[m][2i], w1=weight[m][2i+1]
__global__ void precompute_tbl(const float* __restrict__ weight,
                               float4* __restrict__ tbl) {
    int tid = blockIdx.x * blockDim.x + threadIdx.x;   // 0..16383
    int i = tid >> 8, m = tid & 255;
    float w0 = weight[m * N_SZ + 2 * i];
    float w1 = weight[m * N_SZ + 2 * i + 1];
    float c0, s0, c1, s1;
    __sincosf(w0, &s0, &c0);
    __sincosf(w1, &s1, &c1);
    tbl[i * M_SZ + m] = make_float4(c0, s0, c1, s1);
}

// One block = 4 samples x 8 i-chunk waves (512 thr). Lane: bl=lane>>4 picks the
// sample, ml=lane&15; lane owns m = ml + 16t, t=0..15 (c[16],s[16] rotation
// state in regs). Main loop pure FMA; butterfly is 4 steps serving 4 b's per
// DS instr; all 3*CHI reductions batched so DS chains pipeline. Chunk z-starts
// via one 32 KB LDS exclusive scan.
__global__ __launch_bounds__(512, 2) void arrbm_main(
    const float* __restrict__ vis,     // [B,N]
    const float* __restrict__ hb,      // [M]
    const float* __restrict__ weight,  // [M,N]
    const float4* __restrict__ tbl,    // [I,M]
    float* __restrict__ out)           // [B]
{
    const int tid  = threadIdx.x;
    const int wv   = tid >> 6;          // 0..7 : i-chunk index
    const int lane = tid & 63;
    const int bl   = lane >> 4;         // 0..3 : sample within block
    const int ml   = lane & 15;         // m = ml + 16*t

    __shared__ float  s_vis[BPB * N_SZ];        // 2 KB
    __shared__ float4 s_scan[WPB * 4 * 64];     // 32 KB
    __shared__ float2 s_red[WPB][BPB];
    __shared__ float  s_sz[BPB];

    if (tid < BPB * N_SZ)
        s_vis[tid] = vis[blockIdx.x * (BPB * N_SZ) + tid];
    __syncthreads();

    // Sz filter (wave 0)
    if (wv == 0) {
        float d = 0.f;
        #pragma unroll
        for (int k = 0; k < 4; ++k)
            d += s_vis[bl * N_SZ + 8 * ml + 2 * k] - s_vis[bl * N_SZ + 8 * ml + 2 * k + 1];
        #pragma unroll
        for (int off = 1; off <= 8; off <<= 1)
            d += __shfl_xor(d, off, 64);
        if (ml == 0) s_sz[bl] = d;
    }

    const int i0 = wv * CHI;

    float v0[CHI], v1[CHI];
    #pragma unroll
    for (int j = 0; j < CHI; ++j) {
        v0[j] = s_vis[bl * N_SZ + 2 * (i0 + j)];
        v1[j] = s_vis[bl * N_SZ + 2 * (i0 + j) + 1];
    }

    // local chunk step-sum per owned m (16 elements each, vectorized)
    {
        float ls[16];
        #pragma unroll
        for (int t = 0; t < 16; ++t) {
            const int m = ml + 16 * t;
            const float4* wrow = (const float4*)(weight + (size_t)m * N_SZ) + (i0 >> 1);
            float a = 0.f;
            #pragma unroll
            for (int k = 0; k < CHI / 2; ++k) {
                float4 w4 = wrow[k];
                a += v0[2*k]   * w4.x + v1[2*k]   * w4.y
                   + v0[2*k+1] * w4.z + v1[2*k+1] * w4.w;
            }
            ls[t] = a;
        }
        #pragma unroll
        for (int k = 0; k < 4; ++k)
            s_scan[(wv * 4 + k) * 64 + lane] =
                make_float4(ls[4*k], ls[4*k+1], ls[4*k+2], ls[4*k+3]);
    }
    __syncthreads();

    // exclusive scan: z at chunk start for each owned m
    float z0[16];
    #pragma unroll
    for (int t = 0; t < 16; ++t) z0[t] = 0.f;
    for (int wp = 0; wp < wv; ++wp) {
        #pragma unroll
        for (int k = 0; k < 4; ++k) {
            float4 r = s_scan[(wp * 4 + k) * 64 + lane];
            z0[4*k]   += r.x; z0[4*k+1] += r.y;
            z0[4*k+2] += r.z; z0[4*k+3] += r.w;
        }
    }

    // init rotation state at chunk start (only trans ops here)
    float c[16], s[16];
    float pstart = 1.f;
    #pragma unroll
    for (int t = 0; t < 16; ++t) {
        float pre = hb[ml + 16 * t] + z0[t];
        __sincosf(pre, &s[t], &c[t]);
        pstart *= c[t];
    }

    // batched per-i partial products over owned m (pure FMA)
    float q0a[CHI], q1a[CHI], q2a[CHI];
    #pragma unroll
    for (int j = 0; j < CHI; ++j) {
        const int i = i0 + j;
        const float4* trow = tbl + i * M_SZ + ml;
        const float pm = v0[j] * v1[j];
        float q0 = 1.f, q1 = 1.f, q2 = 1.f;
        #pragma unroll
        for (int t = 0; t < 16; ++t) {
            float4 w = trow[16 * t];
            float pw0 = fmaf(-s[t], w.y, c[t] * w.x);   // cos(pre+w0)
            float pw1 = fmaf(-s[t], w.w, c[t] * w.z);   // cos(pre+w1)
            q0 *= c[t]; q1 *= pw0; q2 *= pw1;
            float cs = fmaf(-pm, w.y * w.w, w.x * w.z);             // cos(step)
            float ss = fmaf(v1[j], w.x * w.w, v0[j] * (w.y * w.z)); // sin(step)
            float cn = fmaf(-s[t], ss, c[t] * cs);
            float sn = fmaf( c[t], ss, s[t] * cs);
            c[t] = cn; s[t] = sn;
        }
        q0a[j] = q0; q1a[j] = q1; q2a[j] = q2;
    }

    // 3*CHI independent 4-step butterflies, back-to-back (DS chains pipeline)
    #pragma unroll
    for (int j = 0; j < CHI; ++j) {
        #pragma unroll
        for (int off = 1; off <= 8; off <<= 1) {
            q0a[j] *= __shfl_xor(q0a[j], off, 64);
            q1a[j] *= __shfl_xor(q1a[j], off, 64);
            q2a[j] *= __shfl_xor(q2a[j], off, 64);
        }
    }

    float psi = 1.f, acc = 1.f;
    #pragma unroll
    for (int j = 0; j < CHI; ++j) {
        float n2 = 4.f * q0a[j] * q0a[j] + 2.f * q1a[j] * q1a[j] + 2.f * q2a[j] * q2a[j];
        acc *= rsqrtf(n2);
        psi *= q0a[j];
    }

    // chunk telescope correction: x prod_m c_end/c_start
    float pend = 1.f;
    #pragma unroll
    for (int t = 0; t < 16; ++t) pend *= c[t];
    float r = pend / pstart;
    #pragma unroll
    for (int off = 1; off <= 8; off <<= 1)
        r *= __shfl_xor(r, off, 64);
    psi *= r;

    if (ml == 0) s_red[wv][bl] = make_float2(psi, acc);
    __syncthreads();

    if (tid < BPB) {
        float P = 1.f;
        #pragma unroll
        for (int w = 0; w < WPB; ++w)
            P *= s_red[w][tid].x * s_red[w][tid].y;
        out[blockIdx.x * BPB + tid] = (s_sz[tid] != 0.f) ? 0.f : P;
    }
}

extern "C" void kernel_launch(void* const* d_in, const int* in_sizes, int n_in,
                              void* d_out, int out_size, void* d_ws, size_t ws_size,
                              hipStream_t stream) {
    const float* vis    = (const float*)d_in[0];  // [B,N]
    const float* hb     = (const float*)d_in[1];  // [M]
    const float* weight = (const float*)d_in[2];  // [M,N]
    float* out  = (float*)d_out;                  // [B]
    float4* tbl = (float4*)d_ws;                  // [I*M] = 256 KB

    precompute_tbl<<<64, 256, 0, stream>>>(weight, tbl);
    arrbm_main<<<B_SZ / BPB, 64 * WPB, 0, stream>>>(vis, hb, weight, tbl, out);
}

// Round 6
// 109.121 us; speedup vs baseline: 1.4306x; 1.0390x over previous
//
#include <hip/hip_runtime.h>
#include <hip/hip_fp16.h>
#include <math.h>

#define B_SZ 1024
#define N_SZ 128
#define M_SZ 256
#define I_SZ 64
#define NCH  16                // i-chunks (one per wave in main kernel)
#define CHI  (I_SZ / NCH)      // 4 i's per chunk

// ---------------- kernel 1: prefix checkpoints + Sz flags ----------------
// grid 256 blocks x 256 thr; thread = m, block covers 4 b.
// Z[b][c][m] (fp16) = hb[m] + sum_{k<8c} vis[b,k]*W[m,k]
__global__ __launch_bounds__(256) void ck_kernel(
    const float* __restrict__ vis, const float* __restrict__ hb,
    const float* __restrict__ weight, __half* __restrict__ Z,
    float* __restrict__ flag)
{
    const int m  = threadIdx.x;
    const int b0 = blockIdx.x * 4;
    const float bias = hb[m];
    float z[4], sz[4];
    #pragma unroll
    for (int j = 0; j < 4; ++j) { z[j] = bias; sz[j] = 0.f; }

    for (int c = 0; c < NCH; ++c) {
        #pragma unroll
        for (int j = 0; j < 4; ++j)
            Z[((size_t)(b0 + j) * NCH + c) * M_SZ + m] = __float2half(z[j]);
        const float4 wa = *(const float4*)&weight[m * N_SZ + 8 * c];
        const float4 wb = *(const float4*)&weight[m * N_SZ + 8 * c + 4];
        #pragma unroll
        for (int j = 0; j < 4; ++j) {
            const float* vr = vis + (size_t)(b0 + j) * N_SZ + 8 * c; // uniform -> s_load
            const float a0 = vr[0], a1 = vr[1], a2 = vr[2], a3 = vr[3];
            const float a4 = vr[4], a5 = vr[5], a6 = vr[6], a7 = vr[7];
            z[j] += a0*wa.x + a1*wa.y + a2*wa.z + a3*wa.w
                  + a4*wb.x + a5*wb.y + a6*wb.z + a7*wb.w;
            sz[j] += (a0 - a1) + (a2 - a3) + (a4 - a5) + (a6 - a7);
        }
    }
    if (m == 0) {
        #pragma unroll
        for (int j = 0; j < 4; ++j)
            flag[b0 + j] = (sz[j] != 0.f) ? 0.f : 1.f;
    }
}

// ---------------- kernel 2: main ----------------
// grid 256 blocks x 1024 thr = 16 waves; wave wv = i-chunk [4wv, 4wv+4).
// Lane: bl = lane>>4 picks b, ml = lane&15; lane owns m = ml + 16t, t=0..15
// with a single running scalar zz per t (no big live arrays -> no spill).
// Per i: 3 __cosf per m; m-reduction = 4-hop butterfly serving 4 b per DS op,
// 13 chains batched. psi telescopes within the chunk:
//   prod_i cos(full_i) = q0[1]*q0[2]*q0[3]*cos(z_end).
__global__ __launch_bounds__(1024, 4) void arrbm_main(
    const float* __restrict__ vis, const float* __restrict__ weight,
    const __half* __restrict__ Z, const float* __restrict__ flag,
    float* __restrict__ out)
{
    const int tid  = threadIdx.x;
    const int wv   = tid >> 6;          // chunk 0..15
    const int lane = tid & 63;
    const int bl   = lane >> 4, ml = lane & 15;
    const int b    = blockIdx.x * 4 + bl;
    const int i0   = wv * CHI;

    __shared__ float2 s_red[NCH][4];

    float v0[CHI], v1[CHI];
    #pragma unroll
    for (int j = 0; j < CHI; ++j) {
        const float2 vv = *(const float2*)&vis[(size_t)b * N_SZ + 2 * (i0 + j)];
        v0[j] = vv.x; v1[j] = vv.y;
    }

    float q0a[CHI], q1a[CHI], q2a[CHI];
    #pragma unroll
    for (int j = 0; j < CHI; ++j) { q0a[j] = 1.f; q1a[j] = 1.f; q2a[j] = 1.f; }
    float pend = 1.f;

    const __half* zrow = Z + ((size_t)b * NCH + wv) * M_SZ + ml;

    #pragma unroll
    for (int t = 0; t < 16; ++t) {
        float zz = __half2float(zrow[16 * t]);
        const float* wr = weight + (size_t)(ml + 16 * t) * N_SZ + 2 * i0;
        const float4 wa = *(const float4*)wr;        // (w0,w1) for i0, i0+1
        const float4 wb = *(const float4*)(wr + 4);  // (w0,w1) for i0+2, i0+3
        // j = 0
        q0a[0] *= __cosf(zz); q1a[0] *= __cosf(zz + wa.x); q2a[0] *= __cosf(zz + wa.y);
        zz += v0[0] * wa.x + v1[0] * wa.y;
        // j = 1
        q0a[1] *= __cosf(zz); q1a[1] *= __cosf(zz + wa.z); q2a[1] *= __cosf(zz + wa.w);
        zz += v0[1] * wa.z + v1[1] * wa.w;
        // j = 2
        q0a[2] *= __cosf(zz); q1a[2] *= __cosf(zz + wb.x); q2a[2] *= __cosf(zz + wb.y);
        zz += v0[2] * wb.x + v1[2] * wb.y;
        // j = 3
        q0a[3] *= __cosf(zz); q1a[3] *= __cosf(zz + wb.z); q2a[3] *= __cosf(zz + wb.w);
        zz += v0[3] * wb.z + v1[3] * wb.w;
        pend *= __cosf(zz);                          // cos(full at chunk end)
    }

    // 13 independent 4-hop butterflies within 16-lane groups (hop-major: pipelines)
    #pragma unroll
    for (int off = 1; off <= 8; off <<= 1) {
        #pragma unroll
        for (int j = 0; j < CHI; ++j) {
            q0a[j] *= __shfl_xor(q0a[j], off, 64);
            q1a[j] *= __shfl_xor(q1a[j], off, 64);
            q2a[j] *= __shfl_xor(q2a[j], off, 64);
        }
        pend *= __shfl_xor(pend, off, 64);
    }

    float acc = 1.f;
    #pragma unroll
    for (int j = 0; j < CHI; ++j)
        acc *= rsqrtf(4.f * q0a[j] * q0a[j] + 2.f * q1a[j] * q1a[j] + 2.f * q2a[j] * q2a[j]);
    float psi = pend;
    #pragma unroll
    for (int j = 1; j < CHI; ++j) psi *= q0a[j];

    if (ml == 0) s_red[wv][bl] = make_float2(psi, acc);
    __syncthreads();

    if (tid < 4) {
        float P = 1.f;
        #pragma unroll
        for (int w = 0; w < NCH; ++w) P *= s_red[w][tid].x * s_red[w][tid].y;
        out[blockIdx.x * 4 + tid] = P * flag[blockIdx.x * 4 + tid];
    }
}

extern "C" void kernel_launch(void* const* d_in, const int* in_sizes, int n_in,
                              void* d_out, int out_size, void* d_ws, size_t ws_size,
                              hipStream_t stream) {
    const float* vis    = (const float*)d_in[0];  // [B,N]
    const float* hb     = (const float*)d_in[1];  // [M]
    const float* weight = (const float*)d_in[2];  // [M,N]
    float* out = (float*)d_out;                   // [B]

    __half* Z   = (__half*)d_ws;                                  // 8 MB
    float* flag = (float*)((char*)d_ws +
                           (size_t)B_SZ * NCH * M_SZ * sizeof(__half));

    ck_kernel<<<B_SZ / 4, 256, 0, stream>>>(vis, hb, weight, Z, flag);
    arrbm_main<<<B_SZ / 4, 1024, 0, stream>>>(vis, weight, Z, flag, out);
}